// Round 3
// baseline (483.526 us; speedup 1.0000x reference)
//
#include <hip/hip_runtime.h>
#include <stdint.h>

#define NV 1024
#define EMB 64
#define NBLK 512

typedef __attribute__((ext_vector_type(8))) short bf16x8;
typedef __attribute__((ext_vector_type(4))) float f32x4;

__device__ __forceinline__ unsigned short f2b(float f) {
  unsigned int u = __builtin_bit_cast(unsigned int, f);
  u += 0x7fffu + ((u >> 16) & 1u);   // RNE
  return (unsigned short)(u >> 16);
}
__device__ __forceinline__ float b2f(unsigned short s) {
  unsigned int u = ((unsigned int)s) << 16;
  return __builtin_bit_cast(float, u);
}

__device__ __forceinline__ void gll16(void* lds, const void* gsrc) {
  __builtin_amdgcn_global_load_lds(
      (const __attribute__((address_space(1))) unsigned int*)gsrc,
      (__attribute__((address_space(3))) unsigned int*)lds, 16, 0, 0);
}

// One persistent kernel: prep -> 3 bmm+W2 steps -> readout.
// grid 512 (b=blk>>4, mb=blk&15), 256 threads. 2 blocks/CU guaranteed by
// __launch_bounds__(256,2): 512 threads, ~35KB LDS, VGPR<=256 per wave.
__global__ __launch_bounds__(256, 2) void k_fused(
    const float* __restrict__ graph, const float* __restrict__ Xv,
    const float* __restrict__ W1, const float* __restrict__ W2,
    const float* __restrict__ W3, const float* __restrict__ W4,
    const float* __restrict__ W5, const float* __restrict__ W6,
    const float* __restrict__ W7,
    unsigned short* __restrict__ G16,
    unsigned short* __restrict__ embA,
    unsigned short* __restrict__ embB,
    float* __restrict__ esum_ws, unsigned int* __restrict__ bar,
    float* __restrict__ out)
{
  __shared__ __align__(16) char ldsbuf[32768];  // [A0 8K][B0 8K][A1 8K][B1 8K]
  __shared__ float w34s[EMB];
  __shared__ float degs[EMB];
  __shared__ float xvs[EMB];
  __shared__ float esl[EMB];
  __shared__ float redl[256];
  __shared__ float s6l;

  const int tid = threadIdx.x;
  const int lane = tid & 63;
  const int wv = tid >> 6;
  const int b = blockIdx.x >> 4;
  const int mb = blockIdx.x & 15;
  const int wm = wv >> 1, wn = wv & 1;
  const int l15 = lane & 15, l4 = lane >> 4;

  // ---- software grid barrier (all 512 blocks co-resident) ----
  auto gbar = [&](unsigned int target) {
    __syncthreads();
    if (tid == 0) {
      __threadfence();  // agent-scope release (L2 writeback on gfx950)
      __hip_atomic_fetch_add(bar, 1u, __ATOMIC_RELAXED, __HIP_MEMORY_SCOPE_AGENT);
      while (__hip_atomic_load(bar, __ATOMIC_RELAXED, __HIP_MEMORY_SCOPE_AGENT) < target)
        __builtin_amdgcn_s_sleep(2);
      __threadfence();  // acquire
    }
    __syncthreads();
  };

  // =================== Phase 0: prep ===================
  if (tid < EMB) {
    float s = 0.f;
    const float* w3r = W3 + tid * EMB;
#pragma unroll
    for (int k = 0; k < EMB; ++k) s += w3r[k] * W4[k];
    w34s[tid] = s;
  }
  __syncthreads();
  {
    unsigned short* ebT = (unsigned short*)ldsbuf;  // [64][68]
    const float w1v = W1[lane];
    const float w34v = w34s[lane];
    for (int i = 0; i < 16; ++i) {
      const int rloc = wv * 16 + i;
      const int row = mb * 64 + rloc;
      const float4* gr = (const float4*)(graph + ((size_t)b * NV + row) * NV);
      float part = 0.f;
      ushort4 outp[4];
#pragma unroll
      for (int c = 0; c < 4; ++c) {
        float4 v = gr[c * 64 + lane];
        part += (v.x + v.y) + (v.z + v.w);
        outp[c].x = f2b(v.x); outp[c].y = f2b(v.y);
        outp[c].z = f2b(v.z); outp[c].w = f2b(v.w);
      }
      ushort4* g16r = (ushort4*)(G16 + ((size_t)b * NV + row) * NV);
#pragma unroll
      for (int c = 0; c < 4; ++c) g16r[c * 64 + lane] = outp[c];
#pragma unroll
      for (int d = 1; d < 64; d <<= 1) part += __shfl_xor(part, d);
      const float deg = part;
      const float xv = Xv[b * NV + row];
      if (lane == 0) { degs[rloc] = deg; xvs[rloc] = xv; }
      const float bs = xv * w1v + deg * w34v;
      ebT[lane * 68 + rloc] = f2b(fmaxf(bs, 0.f));
    }
    __syncthreads();
    const int e = tid >> 2, q = tid & 3;
    ushort4* dst = (ushort4*)(embA + ((size_t)(b * EMB + e)) * NV + mb * 64 + q * 16);
    const ushort4* srcr = (const ushort4*)(ebT + e * 68 + q * 16);
#pragma unroll
    for (int c = 0; c < 4; ++c) dst[c] = srcr[c];
  }
  gbar(NBLK);

  // =================== Steps: emb' = relu(base + (G@emb)@W2^T) ===================
  const size_t gbase = ((size_t)b * NV + mb * 64) * NV;
  const size_t ebase = (size_t)b * EMB * NV;

  // W2 fragments + per-lane base factors (persist in regs across steps)
  bf16x8 w2f[2][2];
  float w1e[2], w34e[2];
#pragma unroll
  for (int e16 = 0; e16 < 2; ++e16) {
    const int eg = wn * 32 + e16 * 16 + l15;
    w1e[e16] = W1[eg];
    w34e[e16] = w34s[eg];
#pragma unroll
    for (int kk = 0; kk < 2; ++kk) {
      const float* src = W2 + eg * 64 + kk * 32 + l4 * 8;
      bf16x8 f;
#pragma unroll
      for (int j = 0; j < 8; ++j) f[j] = (short)f2b(src[j]);
      w2f[e16][kk] = f;
    }
  }

  auto do_step = [&](const unsigned short* embin, unsigned short* embout, int s) {
    f32x4 acc[2][2] = {};
    auto STAGE = [&](int bufi, int kt) {
      char* Ad = ldsbuf + bufi * 16384;
      char* Bd = Ad + 8192;
#pragma unroll
      for (int i = 0; i < 2; ++i) {
        const int cc = i * 256 + tid;
        const int lrow = cc >> 3, lcg = cc & 7;
        const int gcg = lcg ^ (lrow & 7);
        gll16(Ad + (i * 256 + wv * 64) * 16,
              G16 + gbase + (size_t)lrow * NV + kt * 64 + gcg * 8);
      }
#pragma unroll
      for (int i = 0; i < 2; ++i) {
        const int cc = i * 256 + tid;
        const int er = cc >> 3, lcg = cc & 7;
        const int gcg = lcg ^ (er & 7);
        gll16(Bd + (i * 256 + wv * 64) * 16,
              embin + ebase + (size_t)er * NV + kt * 64 + gcg * 8);
      }
    };
    STAGE(0, 0);
    int cur = 0;
    for (int kt = 0; kt < 16; ++kt) {
      if (kt < 15) {
        STAGE(cur ^ 1, kt + 1);                     // next tile in flight
        asm volatile("s_waitcnt vmcnt(4)" ::: "memory");  // only cur's 4 done
      } else {
        asm volatile("s_waitcnt vmcnt(0)" ::: "memory");
      }
      __builtin_amdgcn_s_barrier();
      asm volatile("" ::: "memory");
      const char* At = ldsbuf + cur * 16384;
      const char* Bt = At + 8192;
#pragma unroll
      for (int kk = 0; kk < 2; ++kk) {
        bf16x8 af[2], bf[2];
        const int gq = kk * 4 + l4;
#pragma unroll
        for (int m16 = 0; m16 < 2; ++m16) {
          const int row = wm * 32 + m16 * 16 + l15;
          af[m16] = *(const bf16x8*)(At + row * 128 + ((gq ^ (row & 7)) << 4));
        }
#pragma unroll
        for (int n16 = 0; n16 < 2; ++n16) {
          const int er = wn * 32 + n16 * 16 + l15;
          bf[n16] = *(const bf16x8*)(Bt + er * 128 + ((gq ^ (er & 7)) << 4));
        }
#pragma unroll
        for (int m16 = 0; m16 < 2; ++m16)
#pragma unroll
          for (int n16 = 0; n16 < 2; ++n16)
            acc[m16][n16] = __builtin_amdgcn_mfma_f32_16x16x32_bf16(
                af[m16], bf[n16], acc[m16][n16], 0, 0, 0);
      }
      asm volatile("" ::: "memory");
      __builtin_amdgcn_s_barrier();
      cur ^= 1;
    }

    // ---- epilogue: S -> LDS (swizzled bf16, buf0 A region), S @ W2^T ----
    char* St = ldsbuf;
    if (s == 3 && tid < 64) esl[tid] = 0.f;
#pragma unroll
    for (int m16 = 0; m16 < 2; ++m16)
#pragma unroll
      for (int n16 = 0; n16 < 2; ++n16)
#pragma unroll
        for (int r = 0; r < 4; ++r) {
          const int m = wm * 32 + m16 * 16 + l4 * 4 + r;
          const int n = wn * 32 + n16 * 16 + l15;
          const int addr = m * 128 + (((n >> 3) ^ (m & 7)) << 4) + (n & 7) * 2;
          *(unsigned short*)(St + addr) = f2b(acc[m16][n16][r]);
        }
    __syncthreads();

    f32x4 acc2[2][2] = {};
#pragma unroll
    for (int kk = 0; kk < 2; ++kk) {
      bf16x8 sa[2];
      const int gq = kk * 4 + l4;
#pragma unroll
      for (int m16 = 0; m16 < 2; ++m16) {
        const int row = wm * 32 + m16 * 16 + l15;
        sa[m16] = *(const bf16x8*)(St + row * 128 + ((gq ^ (row & 7)) << 4));
      }
#pragma unroll
      for (int m16 = 0; m16 < 2; ++m16)
#pragma unroll
        for (int e16 = 0; e16 < 2; ++e16)
          acc2[m16][e16] = __builtin_amdgcn_mfma_f32_16x16x32_bf16(
              sa[m16], w2f[e16][kk], acc2[m16][e16], 0, 0, 0);
    }

    // + base (from LDS degs/xvs), relu; s<3: global bf16; s==3: LDS f32 + esum
    float* et = (float*)(ldsbuf + 8192);   // [64][65] f32, disjoint from St
#pragma unroll
    for (int m16 = 0; m16 < 2; ++m16) {
      const int ml0 = wm * 32 + m16 * 16 + l4 * 4;
      float xv4[4], dg4[4];
#pragma unroll
      for (int r = 0; r < 4; ++r) { xv4[r] = xvs[ml0 + r]; dg4[r] = degs[ml0 + r]; }
#pragma unroll
      for (int e16 = 0; e16 < 2; ++e16) {
        const int eg = wn * 32 + e16 * 16 + l15;
        if (s < 3) {
          ushort4 pk;
          unsigned short* pks = (unsigned short*)&pk;
#pragma unroll
          for (int r = 0; r < 4; ++r) {
            const float bs = xv4[r] * w1e[e16] + dg4[r] * w34e[e16];
            pks[r] = f2b(fmaxf(acc2[m16][e16][r] + bs, 0.f));
          }
          *(ushort4*)(embout + ((size_t)(b * EMB + eg)) * NV + mb * 64 + ml0) = pk;
        } else {
          float evs = 0.f;
#pragma unroll
          for (int r = 0; r < 4; ++r) {
            const float bs = xv4[r] * w1e[e16] + dg4[r] * w34e[e16];
            const float val = fmaxf(acc2[m16][e16][r] + bs, 0.f);
            et[(ml0 + r) * 65 + eg] = val;
            evs += val;
          }
          atomicAdd(&esl[eg], evs);
        }
      }
    }
    if (s == 3) {
      __syncthreads();
      if (tid < 64) atomicAdd(&esum_ws[b * EMB + tid], esl[tid]);
    }
  };

  do_step(embA, embB, 1);  gbar(2 * NBLK);
  do_step(embB, embA, 2);  gbar(3 * NBLK);
  do_step(embA, embB, 3);  gbar(4 * NBLK);

  // =================== Readout ===================
  // s6 (redundant per block, cheap): s6 = W5a . relu(W6 @ esum)
  if (tid < 64) {
    const float* es = esum_ws + b * EMB;
    float v6 = 0.f;
    const float* w6r = W6 + tid * EMB;
#pragma unroll
    for (int k = 0; k < EMB; ++k) v6 += w6r[k] * es[k];
    float c = W5[tid] * fmaxf(v6, 0.f);
#pragma unroll
    for (int d = 1; d < 64; d <<= 1) c += __shfl_xor(c, d);
    if (tid == 0) s6l = c;
  }
  __syncthreads();
  // per-vertex: out = s6 + W5b . relu(W7 @ emb_v), emb tile (f32) already in LDS
  {
    const float* et = (const float*)(ldsbuf + 8192);
    const int v = tid & 63, eq = tid >> 6;
    float ev[64];
#pragma unroll
    for (int k = 0; k < EMB; ++k) ev[k] = et[v * 65 + k];
    float sp = 0.f;
    for (int e = eq * 16; e < eq * 16 + 16; ++e) {
      const float* w7r = W7 + e * 64;   // wave-uniform -> scalar loads
      float a = 0.f;
#pragma unroll
      for (int k = 0; k < 64; ++k) a += ev[k] * w7r[k];
      sp += W5[64 + e] * fmaxf(a, 0.f);
    }
    redl[tid] = sp;
    __syncthreads();
    if (tid < 64)
      out[b * NV + mb * 64 + tid] =
          s6l + redl[tid] + redl[tid + 64] + redl[tid + 128] + redl[tid + 192];
  }
}

// ---------------------------------------------------------------------------
extern "C" void kernel_launch(void* const* d_in, const int* in_sizes, int n_in,
                              void* d_out, int out_size, void* d_ws, size_t ws_size,
                              hipStream_t stream) {
  const float* graph = (const float*)d_in[0];
  const float* Xv = (const float*)d_in[1];
  const float* W1 = (const float*)d_in[2];
  const float* W2 = (const float*)d_in[3];
  const float* W3 = (const float*)d_in[4];
  const float* W4 = (const float*)d_in[5];
  const float* W5 = (const float*)d_in[6];
  const float* W6 = (const float*)d_in[7];
  const float* W7 = (const float*)d_in[8];
  float* out = (float*)d_out;
  char* ws = (char*)d_ws;

  unsigned short* G16 = (unsigned short*)ws;                         // 64 MB
  unsigned short* embA = (unsigned short*)(ws + (64u << 20));        // 4 MB
  unsigned short* embB = (unsigned short*)(ws + (68u << 20));        // 4 MB
  char* ctrl = ws + (72u << 20);
  unsigned int* bar = (unsigned int*)ctrl;                           // 4 B
  float* esum_ws = (float*)(ctrl + 64);                              // 8 KB

  hipMemsetAsync(ctrl, 0, 64 + 32 * 64 * 4, stream);
  k_fused<<<NBLK, 256, 0, stream>>>(graph, Xv, W1, W2, W3, W4, W5, W6, W7,
                                    G16, embA, embB, esum_ws, bar, out);
}

// Round 4
// 296.753 us; speedup vs baseline: 1.6294x; 1.6294x over previous
//
#include <hip/hip_runtime.h>
#include <stdint.h>

#define NV 1024
#define EMB 64

typedef __attribute__((ext_vector_type(8))) short bf16x8;
typedef __attribute__((ext_vector_type(4))) float f32x4;

__device__ __forceinline__ unsigned short f2b(float f) {
  unsigned int u = __builtin_bit_cast(unsigned int, f);
  u += 0x7fffu + ((u >> 16) & 1u);   // RNE
  return (unsigned short)(u >> 16);
}
__device__ __forceinline__ float b2f(unsigned short s) {
  unsigned int u = ((unsigned int)s) << 16;
  return __builtin_bit_cast(float, u);
}

__device__ __forceinline__ void gll16(void* lds, const void* gsrc) {
  __builtin_amdgcn_global_load_lds(
      (const __attribute__((address_space(1))) unsigned int*)gsrc,
      (__attribute__((address_space(3))) unsigned int*)lds, 16, 0, 0);
}

// XCD-batch swizzle: all 16 blocks of batch b -> XCD b&7 (assumes default
// round-robin xcd = blockIdx % 8; speed-only heuristic).
__device__ __forceinline__ void swz(int j, int& b, int& mb) {
  const int xcd = j & 7, s = j >> 3;
  b = xcd + 8 * (s >> 4);
  mb = s & 15;
}

// ---------------------------------------------------------------------------
// k_prep: deg row-sums, graph f32->bf16, w34 = W3@W4, emb1 = relu(base),
// written transposed embT[b][e][n]. grid 512, 256 threads, full occupancy.
// ---------------------------------------------------------------------------
__global__ __launch_bounds__(256) void k_prep(
    const float* __restrict__ graph, const float* __restrict__ Xv,
    const float* __restrict__ W1, const float* __restrict__ W3,
    const float* __restrict__ W4,
    unsigned short* __restrict__ G16, float* __restrict__ degp,
    float* __restrict__ w34g, unsigned short* __restrict__ embT)
{
  __shared__ float w34s[EMB];
  __shared__ __align__(16) unsigned short ebT[EMB][68];
  const int tid = threadIdx.x;
  int b, mb; swz(blockIdx.x, b, mb);
  if (tid < EMB) {
    float s = 0.f;
    const float* w3r = W3 + tid * EMB;
#pragma unroll
    for (int k = 0; k < EMB; ++k) s += w3r[k] * W4[k];
    w34s[tid] = s;
    if (blockIdx.x == 0) w34g[tid] = s;
  }
  __syncthreads();
  const int wv = tid >> 6, lane = tid & 63;
  const float w1v = W1[lane];
  const float w34v = w34s[lane];
  for (int i = 0; i < 16; ++i) {
    const int rloc = wv * 16 + i;
    const int row = mb * 64 + rloc;
    const float4* gr = (const float4*)(graph + ((size_t)b * NV + row) * NV);
    float part = 0.f;
    ushort4 outp[4];
#pragma unroll
    for (int c = 0; c < 4; ++c) {
      float4 v = gr[c * 64 + lane];
      part += (v.x + v.y) + (v.z + v.w);
      outp[c].x = f2b(v.x); outp[c].y = f2b(v.y);
      outp[c].z = f2b(v.z); outp[c].w = f2b(v.w);
    }
    ushort4* g16r = (ushort4*)(G16 + ((size_t)b * NV + row) * NV);
#pragma unroll
    for (int c = 0; c < 4; ++c) g16r[c * 64 + lane] = outp[c];
#pragma unroll
    for (int d = 1; d < 64; d <<= 1) part += __shfl_xor(part, d);
    const float deg = part;
    if (lane == 0) degp[b * NV + row] = deg;
    const float xv = Xv[b * NV + row];
    const float bs = xv * w1v + deg * w34v;
    ebT[lane][rloc] = f2b(fmaxf(bs, 0.f));
  }
  __syncthreads();
  const int e = tid >> 2, q = tid & 3;
  ushort4* dst = (ushort4*)(embT + ((size_t)(b * EMB + e)) * NV + mb * 64 + q * 16);
  const ushort4* srcr = (const ushort4*)(&ebT[e][q * 16]);
#pragma unroll
  for (int c = 0; c < 4; ++c) dst[c] = srcr[c];
}

// ---------------------------------------------------------------------------
// k_step: embout = relu(base + (G @ embin) @ W2^T). Depth-2 prefetch (3 LDS
// buffers), counted vmcnt. grid 512, 256 threads = 4 waves (2m x 2n of 32x32).
// LAST=1 additionally accumulates emb_sum into esum_ws (f32 atomics).
// ---------------------------------------------------------------------------
template <int LAST>
__global__ __launch_bounds__(256, 4) void k_step(
    const unsigned short* __restrict__ G16,
    const unsigned short* __restrict__ embin,
    unsigned short* __restrict__ embout,
    const float* __restrict__ W2, const float* __restrict__ W1,
    const float* __restrict__ w34g, const float* __restrict__ Xv,
    const float* __restrict__ degp, float* __restrict__ esum_ws)
{
  __shared__ __align__(16) char ldsbuf[49152];   // 3 x [A 8K | B 8K]
  __shared__ float esl[EMB];
  const int tid = threadIdx.x;
  const int lane = tid & 63;
  const int wv = tid >> 6;
  int b, mb; swz(blockIdx.x, b, mb);
  const int wm = wv >> 1, wn = wv & 1;
  const int l15 = lane & 15, l4 = lane >> 4;

  // W2 fragments + per-lane base factors
  bf16x8 w2f[2][2];
  float w1e[2], w34e[2];
#pragma unroll
  for (int e16 = 0; e16 < 2; ++e16) {
    const int eg = wn * 32 + e16 * 16 + l15;
    w1e[e16] = W1[eg];
    w34e[e16] = w34g[eg];
#pragma unroll
    for (int kk = 0; kk < 2; ++kk) {
      const float* src = W2 + eg * 64 + kk * 32 + l4 * 8;
      bf16x8 f;
#pragma unroll
      for (int j = 0; j < 8; ++j) f[j] = (short)f2b(src[j]);
      w2f[e16][kk] = f;
    }
  }
  if (LAST && tid < EMB) esl[tid] = 0.f;

  f32x4 acc[2][2] = {};
  const size_t gbase = ((size_t)b * NV + mb * 64) * NV;
  const size_t ebase = (size_t)b * EMB * NV;

  auto STAGE = [&](int bufi, int kt) {
    char* Ad = ldsbuf + bufi * 16384;
    char* Bd = Ad + 8192;
#pragma unroll
    for (int i = 0; i < 2; ++i) {
      const int cc = i * 256 + tid;
      const int lrow = cc >> 3, lcg = cc & 7;
      const int gcg = lcg ^ (lrow & 7);
      gll16(Ad + (i * 256 + wv * 64) * 16,
            G16 + gbase + (size_t)lrow * NV + kt * 64 + gcg * 8);
    }
#pragma unroll
    for (int i = 0; i < 2; ++i) {
      const int cc = i * 256 + tid;
      const int er = cc >> 3, lcg = cc & 7;
      const int gcg = lcg ^ (er & 7);
      gll16(Bd + (i * 256 + wv * 64) * 16,
            embin + ebase + (size_t)er * NV + kt * 64 + gcg * 8);
    }
  };

  STAGE(0, 0);
  STAGE(1, 1);
  for (int kt = 0; kt < 16; ++kt) {
    if (kt < 14) {
      STAGE((kt + 2) % 3, kt + 2);                      // 2 tiles in flight
      asm volatile("s_waitcnt vmcnt(8)" ::: "memory");  // tile kt done
    } else if (kt == 14) {
      asm volatile("s_waitcnt vmcnt(4)" ::: "memory");
    } else {
      asm volatile("s_waitcnt vmcnt(0)" ::: "memory");
    }
    __builtin_amdgcn_s_barrier();
    asm volatile("" ::: "memory");
    const char* At = ldsbuf + (kt % 3) * 16384;
    const char* Bt = At + 8192;
#pragma unroll
    for (int kk = 0; kk < 2; ++kk) {
      bf16x8 af[2], bfr[2];
      const int gq = kk * 4 + l4;
#pragma unroll
      for (int m16 = 0; m16 < 2; ++m16) {
        const int row = wm * 32 + m16 * 16 + l15;
        af[m16] = *(const bf16x8*)(At + row * 128 + ((gq ^ (row & 7)) << 4));
      }
#pragma unroll
      for (int n16 = 0; n16 < 2; ++n16) {
        const int er = wn * 32 + n16 * 16 + l15;
        bfr[n16] = *(const bf16x8*)(Bt + er * 128 + ((gq ^ (er & 7)) << 4));
      }
#pragma unroll
      for (int m16 = 0; m16 < 2; ++m16)
#pragma unroll
        for (int n16 = 0; n16 < 2; ++n16)
          acc[m16][n16] = __builtin_amdgcn_mfma_f32_16x16x32_bf16(
              af[m16], bfr[n16], acc[m16][n16], 0, 0, 0);
    }
    asm volatile("" ::: "memory");
    __builtin_amdgcn_s_barrier();
  }

  // ---- epilogue: S -> LDS (swizzled bf16, buf0), then S @ W2^T ----
  char* St = ldsbuf;
#pragma unroll
  for (int m16 = 0; m16 < 2; ++m16)
#pragma unroll
    for (int n16 = 0; n16 < 2; ++n16)
#pragma unroll
      for (int r = 0; r < 4; ++r) {
        const int m = wm * 32 + m16 * 16 + l4 * 4 + r;
        const int n = wn * 32 + n16 * 16 + l15;
        const int addr = m * 128 + (((n >> 3) ^ (m & 7)) << 4) + (n & 7) * 2;
        *(unsigned short*)(St + addr) = f2b(acc[m16][n16][r]);
      }
  __syncthreads();

  f32x4 acc2[2][2] = {};
#pragma unroll
  for (int kk = 0; kk < 2; ++kk) {
    bf16x8 sa[2];
    const int gq = kk * 4 + l4;
#pragma unroll
    for (int m16 = 0; m16 < 2; ++m16) {
      const int row = wm * 32 + m16 * 16 + l15;
      sa[m16] = *(const bf16x8*)(St + row * 128 + ((gq ^ (row & 7)) << 4));
    }
#pragma unroll
    for (int m16 = 0; m16 < 2; ++m16)
#pragma unroll
      for (int e16 = 0; e16 < 2; ++e16)
        acc2[m16][e16] = __builtin_amdgcn_mfma_f32_16x16x32_bf16(
            sa[m16], w2f[e16][kk], acc2[m16][e16], 0, 0, 0);
  }

  // + base, relu, write transposed bf16; LAST also accumulates emb_sum
#pragma unroll
  for (int m16 = 0; m16 < 2; ++m16) {
    const int ml0 = wm * 32 + m16 * 16 + l4 * 4;
    const int m0 = mb * 64 + ml0;
    float xv4[4], dg4[4];
#pragma unroll
    for (int r = 0; r < 4; ++r) {
      xv4[r] = Xv[b * NV + m0 + r];
      dg4[r] = degp[b * NV + m0 + r];
    }
#pragma unroll
    for (int e16 = 0; e16 < 2; ++e16) {
      const int eg = wn * 32 + e16 * 16 + l15;
      ushort4 pk;
      unsigned short* pks = (unsigned short*)&pk;
      float evs = 0.f;
#pragma unroll
      for (int r = 0; r < 4; ++r) {
        const float bs = xv4[r] * w1e[e16] + dg4[r] * w34e[e16];
        const float val = fmaxf(acc2[m16][e16][r] + bs, 0.f);
        pks[r] = f2b(val);
        evs += val;
      }
      *(ushort4*)(embout + ((size_t)(b * EMB + eg)) * NV + m0) = pk;
      if (LAST) atomicAdd(&esl[eg], evs);
    }
  }
  if (LAST) {
    __syncthreads();
    if (tid < EMB) atomicAdd(&esum_ws[b * EMB + tid], esl[tid]);
  }
}

// ---------------------------------------------------------------------------
// k_out: out[b,n] = s6[b] + sum_e W5[64+e]*relu(W7 @ emb_v); s6 from esum_ws.
// grid 32*4 (256 vertices each), 256 threads.
// ---------------------------------------------------------------------------
__global__ __launch_bounds__(256) void k_out(
    const unsigned short* __restrict__ embT, const float* __restrict__ W7,
    const float* __restrict__ W5, const float* __restrict__ W6,
    const float* __restrict__ esum_ws, float* __restrict__ out)
{
  __shared__ __align__(16) unsigned short et[EMB][256];
  __shared__ float s6l;
  const int tid = threadIdx.x;
  const int b = blockIdx.x >> 2;
  const int n0 = (blockIdx.x & 3) * 256;
#pragma unroll
  for (int i = 0; i < 8; ++i) {
    const int c = i * 256 + tid;
    const int k = c >> 5, off = (c & 31) * 8;
    *(uint4*)&et[k][off] =
        *(const uint4*)(embT + ((size_t)(b * EMB + k)) * NV + n0 + off);
  }
  if (tid < EMB) {
    const float* es = esum_ws + b * EMB;
    float v6 = 0.f;
    const float* w6r = W6 + tid * EMB;
#pragma unroll
    for (int k = 0; k < EMB; ++k) v6 += w6r[k] * es[k];
    float c = W5[tid] * fmaxf(v6, 0.f);
#pragma unroll
    for (int d = 1; d < 64; d <<= 1) c += __shfl_xor(c, d);
    if (tid == 0) s6l = c;
  }
  __syncthreads();
  float ev[64];
#pragma unroll
  for (int k = 0; k < 64; ++k) ev[k] = b2f(et[k][tid]);
  float s7 = 0.f;
  for (int e = 0; e < 64; ++e) {
    const float* w7r = W7 + e * 64;        // wave-uniform -> scalar loads
    float a = 0.f;
#pragma unroll
    for (int k = 0; k < 64; ++k) a += ev[k] * w7r[k];
    s7 += W5[64 + e] * fmaxf(a, 0.f);
  }
  out[b * NV + n0 + tid] = s6l + s7;
}

// ---------------------------------------------------------------------------
extern "C" void kernel_launch(void* const* d_in, const int* in_sizes, int n_in,
                              void* d_out, int out_size, void* d_ws, size_t ws_size,
                              hipStream_t stream) {
  const float* graph = (const float*)d_in[0];
  const float* Xv = (const float*)d_in[1];
  const float* W1 = (const float*)d_in[2];
  const float* W2 = (const float*)d_in[3];
  const float* W3 = (const float*)d_in[4];
  const float* W4 = (const float*)d_in[5];
  const float* W5 = (const float*)d_in[6];
  const float* W6 = (const float*)d_in[7];
  const float* W7 = (const float*)d_in[8];
  float* out = (float*)d_out;
  char* ws = (char*)d_ws;

  unsigned short* G16 = (unsigned short*)ws;                     // 64 MB
  unsigned short* embA = (unsigned short*)(ws + (64u << 20));    // 4 MB
  unsigned short* embB = (unsigned short*)(ws + (68u << 20));    // 4 MB
  float* degp = (float*)(ws + (72u << 20));                      // 128 KB
  float* w34g = (float*)(ws + (72u << 20) + (128u << 10));       // 256 B
  float* esum_ws = (float*)(ws + (72u << 20) + (130u << 10));    // 8 KB

  hipMemsetAsync(esum_ws, 0, 32 * EMB * sizeof(float), stream);
  k_prep<<<512, 256, 0, stream>>>(graph, Xv, W1, W3, W4, G16, degp, w34g, embA);
  k_step<0><<<512, 256, 0, stream>>>(G16, embA, embB, W2, W1, w34g, Xv, degp, esum_ws);
  k_step<0><<<512, 256, 0, stream>>>(G16, embB, embA, W2, W1, w34g, Xv, degp, esum_ws);
  k_step<1><<<512, 256, 0, stream>>>(G16, embA, embB, W2, W1, w34g, Xv, degp, esum_ws);
  k_out<<<128, 256, 0, stream>>>(embB, W7, W5, W6, esum_ws, out);
}